// Round 11
// baseline (180.291 us; speedup 1.0000x reference)
//
#include <hip/hip_runtime.h>
#include <hip/hip_bf16.h>

// B=4, N=2048, D_MODEL=512, H=4, DK=64, DV=128. fp32 in/out, bf16 MFMA.
// Softmax over BATCH axis (4 values) -> in-register per lane.
// R11: kernel-count reduction (5 -> 4). (1) X cast fused into gemm_qkv
// A-staging (fp32 loads + cvt_pk + ds_write; Xb buffer deleted).
// (2) reduce4 fused into gemm_out A-staging (4 partials summed in fp32
// during staging). (3) prep = weights only. attn unchanged from R9/R10.

typedef __attribute__((ext_vector_type(8))) short short8;   // 8 x bf16
typedef __attribute__((ext_vector_type(4))) float floatx4;  // MFMA 16x16 acc
typedef unsigned short u16;
typedef unsigned int u32;

#define MFMA16(a, b, c) __builtin_amdgcn_mfma_f32_16x16x32_bf16((a), (b), (c), 0, 0, 0)

__device__ __forceinline__ u16 f2bf(float f) {
    union { float f; unsigned u; } v; v.f = f;
    unsigned r = v.u + 0x7fffu + ((v.u >> 16) & 1u);  // RNE
    return (u16)(r >> 16);
}

__device__ __forceinline__ float bf2f(u16 b) {
    union { unsigned u; float f; } v; v.u = ((u32)b) << 16;
    return v.f;
}

__device__ __forceinline__ u32 pk2bf(float a, float b) {
#if __has_builtin(__builtin_amdgcn_cvt_pk_bf16_f32)
    typedef __attribute__((ext_vector_type(2))) __bf16 bf16x2;
    union { bf16x2 v; u32 u; } c;
    c.v = __builtin_amdgcn_cvt_pk_bf16_f32(a, b);
    return c.u;
#else
    return (u32)f2bf(a) | ((u32)f2bf(b) << 16);
#endif
}

__device__ __forceinline__ float ex2(float x) {
#if __has_builtin(__builtin_amdgcn_exp2f)
    return __builtin_amdgcn_exp2f(x);
#else
    return exp2f(x);
#endif
}

// async global->LDS, 16B per lane. LDS dest wave-uniform base + lane*16B.
__device__ __forceinline__ void gload_lds16(const u16* g, u16* l) {
    __builtin_amdgcn_global_load_lds(
        (const __attribute__((address_space(1))) void*)(const void*)g,
        (__attribute__((address_space(3))) void*)(void*)l, 16, 0, 0);
}

// ------- weights prep: fp32 [K][N] -> bf16 transposed [N][K] --------------
// Q columns pre-scaled by 0.125*log2(e) so S arrives in log2 domain.
__global__ __launch_bounds__(256) void prep_w_kernel(
    const float* __restrict__ Wq, const float* __restrict__ Wk,
    const float* __restrict__ Wv, const float* __restrict__ Wo,
    u16* __restrict__ WallT, u16* __restrict__ WoT) {
    int i = blockIdx.x * 256 + threadIdx.x;  // 786432 exactly (3072 blocks)
    if (i < 524288) {
        int n = i >> 9, k = i & 511;
        float v;
        if (n < 256)      v = Wq[k * 256 + n] * 0.18033688011f;
        else if (n < 512) v = Wk[k * 256 + (n - 256)];
        else              v = Wv[k * 512 + (n - 512)];
        WallT[i] = f2bf(v);
    } else {
        int j = i - 524288;
        int n = j >> 9, k = j & 511;
        WoT[j] = f2bf(Wo[k * 512 + n]);
    }
}

// ------- QKV GEMM: C = X[M][512] * WallT[N][512]^T, 128x128 tile, 512 thr -
// 8 waves as 2m x 4n, each wave 64x32 (4x2 c-frags). A staged from fp32 x
// with inline bf16 cast (VALU ds_write); B staged via gl_lds.
// Epilogue: LDS roundtrip -> coalesced packed stores.
// Qp: ((((b*4+h)*128+qs)*2+ki)*64+lane)*8+j
// Kp: ((((((b*4+h)*32+kt)*2+half)*2+nj)*2+ki)*64+lane)*8+j
// Vp: ((((((b*4+h)*32+kt)*2+half)*4+ni)*2+w)*64+lane)*8+j
__global__ __launch_bounds__(512) void gemm_qkv_kernel(
    const float* __restrict__ X, const u16* __restrict__ BT,
    u16* __restrict__ Qp, u16* __restrict__ Kp, u16* __restrict__ Vp) {
    __shared__ u16 sm[16896];           // 33 KB; staging uses [0,16384)
    u16* Asl = sm;                       // 128x64, stride 64
    u16* Bsl = sm + 8192;                // 128x64, stride 64
    const int tid = threadIdx.x;
    const int mbase = blockIdx.y * 128;
    const int nbase = blockIdx.x * 128;
    const int wave = tid >> 6, lane = tid & 63;
    const int wm = wave >> 2, wn = wave & 3;   // 2m x 4n
    const int lq = lane & 15, quad = lane >> 4;

    const int srow = wave * 16 + (lane >> 3);  // staging row (+ i*8)
    const int scol = (lane & 7) * 8;
    const u16* gB = BT + (size_t)(nbase + srow) * 512 + scol;
    u16* lB = &Bsl[(wave * 16) * 64];

    const floatx4 z4 = {0.f, 0.f, 0.f, 0.f};
    floatx4 acc[4][2];
#pragma unroll
    for (int i = 0; i < 4; i++)
#pragma unroll
        for (int j = 0; j < 2; j++) acc[i][j] = z4;

    for (int kk = 0; kk < 8; kk++) {
        const int kb = kk << 6;
        if (kk) __syncthreads();
#pragma unroll
        for (int i = 0; i < 2; i++) {
            // A: fp32 load + inline cast + LDS write
            const float* ga = X + (size_t)(mbase + srow + i * 8) * 512 + kb + scol;
            float4 v0 = *(const float4*)ga;
            float4 v1 = *(const float4*)(ga + 4);
            union { short8 s; u32 u[4]; } p;
            p.u[0] = pk2bf(v0.x, v0.y);
            p.u[1] = pk2bf(v0.z, v0.w);
            p.u[2] = pk2bf(v1.x, v1.y);
            p.u[3] = pk2bf(v1.z, v1.w);
            *(short8*)&Asl[(srow + i * 8) * 64 + scol] = p.s;
            // B: async global->LDS
            gload_lds16(gB + kb + (size_t)(i * 8) * 512, lB + (i * 8) * 64);
        }
        __syncthreads();
#pragma unroll
        for (int ki = 0; ki < 2; ki++) {
            short8 af[4], bf[2];
#pragma unroll
            for (int mi = 0; mi < 4; mi++)
                af[mi] = *(const short8*)&Asl[(wm * 64 + mi * 16 + lq) * 64 + ki * 32 + quad * 8];
#pragma unroll
            for (int ni = 0; ni < 2; ni++)
                bf[ni] = *(const short8*)&Bsl[(wn * 32 + ni * 16 + lq) * 64 + ki * 32 + quad * 8];
#pragma unroll
            for (int mi = 0; mi < 4; mi++)
#pragma unroll
                for (int ni = 0; ni < 2; ni++)
                    acc[mi][ni] = MFMA16(af[mi], bf[ni], acc[mi][ni]);
        }
    }
    // ---- epilogue phase 1: C-tile -> sm (stride 132; V-tiles transposed).
    __syncthreads();
    const bool vtile = (nbase >= 512);
#pragma unroll
    for (int mi = 0; mi < 4; mi++)
#pragma unroll
        for (int ni = 0; ni < 2; ni++) {
            int cl = wn * 32 + ni * 16 + lq;
#pragma unroll
            for (int r = 0; r < 4; r++) {
                int rl = wm * 64 + mi * 16 + quad * 4 + r;
                if (vtile) sm[cl * 132 + rl] = f2bf(acc[mi][ni][r]);  // transposed
                else       sm[rl * 132 + cl] = f2bf(acc[mi][ni][r]);
            }
        }
    __syncthreads();
    // ---- phase 2: 32 coalesced 1KB wave-lines (4 per wave). ----
    const int b = mbase >> 11;
    const int keyb = mbase & 2047;
    if (nbase < 256) {                        // Q tile
        const int hq = nbase >> 6;           // {0,2}
        const int qs_base = keyb >> 4;
#pragma unroll
        for (int t = 0; t < 4; t++) {
            int l = wave * 4 + t;
            int qs2 = l >> 2, h2 = (l >> 1) & 1, ki = l & 1;
            int qd = lane >> 4, lqq = lane & 15;
            short8 v = *(const short8*)&sm[(qs2 * 16 + lqq) * 132 + h2 * 64 + ki * 32 + qd * 8];
            int h = hq + h2;
            size_t base = ((size_t)(((b * 4 + h) * 128 + (qs_base + qs2)) * 2 + ki) * 64 + lane) << 3;
            *(short8*)&Qp[base] = v;
        }
    } else if (nbase < 512) {                 // K tile
        const int hb = (nbase - 256) >> 6;   // {0,2}
        const int ktb = keyb >> 6;
#pragma unroll
        for (int t = 0; t < 4; t++) {
            int l = wave * 4 + t;
            int kt2 = l >> 4, hf = (l >> 3) & 1, nj = (l >> 2) & 1;
            int h2 = (l >> 1) & 1, ki = l & 1;
            int quadk = lane >> 4, lqk = lane & 15;
            short8 v = *(const short8*)&sm[(kt2 * 64 + hf * 32 + lqk * 2 + nj) * 132 +
                                           h2 * 64 + ki * 32 + quadk * 8];
            int h = hb + h2;
            size_t base = ((size_t)(((((b * 4 + h) * 32 + (ktb + kt2)) * 2 + hf) * 2 + nj)
                                    * 2 + ki) * 64 + lane) << 3;
            *(short8*)&Kp[base] = v;
        }
    } else {                                  // V tile (sm transposed)
        const int h = (nbase - 512) >> 7;    // tile spans one head
        const int ktb = keyb >> 6;
#pragma unroll
        for (int t = 0; t < 4; t++) {
            int l = wave * 4 + t;
            int kt2 = l >> 4, hf = (l >> 3) & 1, niv = (l >> 1) & 3, wv = l & 1;
            int quadv = lane >> 4, lqv = lane & 15;
            short8 v = *(const short8*)&sm[(hf * 64 + niv * 16 + lqv) * 132 +
                                           kt2 * 64 + wv * 32 + quadv * 8];
            size_t base = ((size_t)(((((b * 4 + h) * 32 + (ktb + kt2)) * 2 + hf) * 4 + niv)
                                    * 2 + wv) * 64 + lane) << 3;
            *(short8*)&Vp[base] = v;
        }
    }
}

// ------- out GEMM + fused reduce: C fp32 = (P0+P1+P2+P3)[M][512] * WoT^T --
// 64x128 tile, 512 thr, 8 waves as 2m x 4n (32x32 each). A staged by
// loading the 4 bf16 partials, summing in fp32, writing bf16 to LDS.
__global__ __launch_bounds__(512) void gemm_out_kernel(
    const u16* __restrict__ Pp, const u16* __restrict__ BT,
    float* __restrict__ Cf) {
    __shared__ u16 Asl[64 * 64];
    __shared__ u16 Bsl[128 * 64];
    const size_t S = (size_t)8192 * 512;
    const int tid = threadIdx.x;
    const int mbase = blockIdx.y * 64;
    const int nbase = blockIdx.x * 128;
    const int wave = tid >> 6, lane = tid & 63;
    const int wm = wave >> 2, wn = wave & 3;
    const int lq = lane & 15, quad = lane >> 4;

    const int srowA = wave * 8 + (lane >> 3);   // A staging row (64 rows)
    const int scol = (lane & 7) * 8;
    const u16* gB = BT + (size_t)(nbase + wave * 16 + (lane >> 3)) * 512 + scol;
    u16* lB = &Bsl[(wave * 16) * 64];

    const floatx4 z4 = {0.f, 0.f, 0.f, 0.f};
    floatx4 acc[2][2];
#pragma unroll
    for (int i = 0; i < 2; i++)
#pragma unroll
        for (int j = 0; j < 2; j++) acc[i][j] = z4;

    for (int kk = 0; kk < 8; kk++) {
        const int kb = kk << 6;
        if (kk) __syncthreads();
        {   // A: load 4 partials, sum fp32, write bf16 to LDS
            const u16* pa = Pp + (size_t)(mbase + srowA) * 512 + kb + scol;
            short8 a0 = *(const short8*)pa;
            short8 a1 = *(const short8*)(pa + S);
            short8 a2 = *(const short8*)(pa + 2 * S);
            short8 a3 = *(const short8*)(pa + 3 * S);
            float f[8];
#pragma unroll
            for (int j = 0; j < 8; j++)
                f[j] = bf2f((u16)a0[j]) + bf2f((u16)a1[j]) +
                       bf2f((u16)a2[j]) + bf2f((u16)a3[j]);
            union { short8 s; u32 u[4]; } o;
            o.u[0] = pk2bf(f[0], f[1]);
            o.u[1] = pk2bf(f[2], f[3]);
            o.u[2] = pk2bf(f[4], f[5]);
            o.u[3] = pk2bf(f[6], f[7]);
            *(short8*)&Asl[srowA * 64 + scol] = o.s;
        }
        gload_lds16(gB + kb, lB);
        gload_lds16(gB + kb + (size_t)8 * 512, lB + 8 * 64);
        __syncthreads();
#pragma unroll
        for (int ki = 0; ki < 2; ki++) {
            short8 af[2], bf[2];
#pragma unroll
            for (int mi = 0; mi < 2; mi++)
                af[mi] = *(const short8*)&Asl[(wm * 32 + mi * 16 + lq) * 64 + ki * 32 + quad * 8];
#pragma unroll
            for (int ni = 0; ni < 2; ni++)
                bf[ni] = *(const short8*)&Bsl[(wn * 32 + ni * 16 + lq) * 64 + ki * 32 + quad * 8];
#pragma unroll
            for (int mi = 0; mi < 2; mi++)
#pragma unroll
                for (int ni = 0; ni < 2; ni++)
                    acc[mi][ni] = MFMA16(af[mi], bf[ni], acc[mi][ni]);
        }
    }
#pragma unroll
    for (int mi = 0; mi < 2; mi++)
#pragma unroll
        for (int ni = 0; ni < 2; ni++)
#pragma unroll
            for (int r = 0; r < 4; r++)
                Cf[(size_t)(mbase + wm * 32 + mi * 16 + quad * 4 + r) * 512 +
                   (nbase + wn * 32 + ni * 16 + lq)] = acc[mi][ni][r];
}

// ---------------- fused attention (unchanged from R9/R10) ----------------
__global__ __launch_bounds__(512) void attn_kernel(const u16* __restrict__ Qp,
                                                   const u16* __restrict__ Kp,
                                                   const u16* __restrict__ Vp,
                                                   u16* __restrict__ Pp) {
    __shared__ u16 pl[2 * 4 * 4096];  // [buf][mi][b*16+q][64], 64 KB exactly
    const int bx = blockIdx.x;
    const int h = bx & 3;
    const int ck = (bx >> 2) & 3;
    const int qt = bx >> 4;                     // [0,32)
    const int tid = threadIdx.x;
    const int wave = tid >> 6, lane = tid & 63;
    const int mi = wave & 3, half = wave >> 2;  // S phase roles
    const int dq = wave;                        // PV phase: dv-16-slice
    const int half_v = dq >> 2, ni_v = dq & 3;
    const int lq = lane & 15, quad = lane >> 4;
    const int qs = qt * 4 + mi;

    short8 aq[4][2];
#pragma unroll
    for (int b = 0; b < 4; b++)
#pragma unroll
        for (int ki = 0; ki < 2; ki++)
            aq[b][ki] = *(const short8*)&Qp[
                ((size_t)((((b * 4 + h) * 128 + qs) * 2 + ki) * 64 + lane) << 3)];

    const floatx4 z4 = {0.f, 0.f, 0.f, 0.f};
    floatx4 oacc[4][4];  // [b][m2]
#pragma unroll
    for (int b = 0; b < 4; b++)
#pragma unroll
        for (int m2 = 0; m2 < 4; m2++) oacc[b][m2] = z4;

    for (int kt = ck * 8; kt < ck * 8 + 8; kt++) {
        u16* plb = &pl[((kt & 1) * 4 + mi) * 4096];
        u16* plbuf = &pl[(kt & 1) * 4 * 4096];
        floatx4 s[4][2];
#pragma unroll
        for (int b = 0; b < 4; b++) {
            const u16* kb = Kp +
                ((size_t)((((b * 4 + h) * 32 + kt) * 2 + half) * 2) << 10) +
                lane * 8;
#pragma unroll
            for (int nj = 0; nj < 2; nj++) {
                s[b][nj] = z4;
#pragma unroll
                for (int ki = 0; ki < 2; ki++)
                    s[b][nj] = MFMA16(aq[b][ki],
                                      *(const short8*)(kb + (nj * 2 + ki) * 512),
                                      s[b][nj]);
            }
        }
        short8 vf[4][2];
#pragma unroll
        for (int b = 0; b < 4; b++) {
            const u16* vb = Vp +
                ((size_t)(((((b * 4 + h) * 32 + kt) * 2 + half_v) * 4 + ni_v) * 2) << 9) +
                lane * 8;
            vf[b][0] = *(const short8*)vb;
            vf[b][1] = *(const short8*)(vb + 512);
        }
#pragma unroll
        for (int r = 0; r < 4; r++) {
            float e0a = ex2(s[0][0][r]), e0b = ex2(s[0][1][r]);
            float e1a = ex2(s[1][0][r]), e1b = ex2(s[1][1][r]);
            float e2a = ex2(s[2][0][r]), e2b = ex2(s[2][1][r]);
            float e3a = ex2(s[3][0][r]), e3b = ex2(s[3][1][r]);
            float ia = __builtin_amdgcn_rcpf(e0a + e1a + e2a + e3a);
            float ib = __builtin_amdgcn_rcpf(e0b + e1b + e2b + e3b);
            int q = quad * 4 + r;
            int col = (half * 32 + 2 * lq) ^ ((q & 7) * 8);  // XOR swizzle
            *(u32*)&plb[(0 * 16 + q) * 64 + col] = pk2bf(e0a * ia, e0b * ib);
            *(u32*)&plb[(1 * 16 + q) * 64 + col] = pk2bf(e1a * ia, e1b * ib);
            *(u32*)&plb[(2 * 16 + q) * 64 + col] = pk2bf(e2a * ia, e2b * ib);
            *(u32*)&plb[(3 * 16 + q) * 64 + col] = pk2bf(e3a * ia, e3b * ib);
        }
        __syncthreads();
        const int sw = (lq & 7) * 8;
#pragma unroll
        for (int b = 0; b < 4; b++) {
#pragma unroll
            for (int m2 = 0; m2 < 4; m2++) {
                const u16* pm = plbuf + m2 * 4096;
                short8 ap0 = *(const short8*)&pm[(b * 16 + lq) * 64 + ((quad * 8) ^ sw)];
                short8 ap1 = *(const short8*)&pm[(b * 16 + lq) * 64 + ((32 + quad * 8) ^ sw)];
                oacc[b][m2] = MFMA16(ap0, vf[b][0], oacc[b][m2]);
                oacc[b][m2] = MFMA16(ap1, vf[b][1], oacc[b][m2]);
            }
        }
    }
    u16* Pc = Pp + (size_t)ck * (8192 * 512);
#pragma unroll
    for (int b = 0; b < 4; b++)
#pragma unroll
        for (int m2 = 0; m2 < 4; m2++)
#pragma unroll
            for (int r = 0; r < 4; r++)
                Pc[(size_t)(b * 2048 + qt * 64 + m2 * 16 + quad * 4 + r) * 512 +
                   h * 128 + dq * 16 + lq] = f2bf(oacc[b][m2][r]);
}

extern "C" void kernel_launch(void* const* d_in, const int* in_sizes, int n_in,
                              void* d_out, int out_size, void* d_ws, size_t ws_size,
                              hipStream_t stream) {
    const float* x  = (const float*)d_in[0];
    const float* Wq = (const float*)d_in[1];
    const float* Wk = (const float*)d_in[2];
    const float* Wv = (const float*)d_in[3];
    const float* Wo = (const float*)d_in[4];
    float* out = (float*)d_out;

    // Workspace map (48.5 MB). Pp[0..4) partials occupy [0, 32MB); WallT
    // (1MB) OVERLAID at the start -- dead before attn writes partials.
    char* ws = (char*)d_ws;
    u16* Pp    = (u16*)ws;                                   // 4 x 8MB bf16
    u16* WallT = (u16*)ws;                                   // overlay [0,1MB)
    char* tail = ws + (size_t)32 * 1024 * 1024;
    u16* WoT   = (u16*)tail; tail += (size_t)512 * 512 * 2;  // 0.5MB
    u16* Qp    = (u16*)tail; tail += (size_t)8192 * 256 * 2; // 4MB
    u16* Kp    = (u16*)tail; tail += (size_t)8192 * 256 * 2; // 4MB
    u16* Vp    = (u16*)tail; tail += (size_t)8192 * 512 * 2; // 8MB

    prep_w_kernel<<<3072, 256, 0, stream>>>(Wq, Wk, Wv, Wo, WallT, WoT);
    // QKV = X @ [Wq|Wk|Wv] (X cast fused into A-staging) -> Qp/Kp/Vp packed
    gemm_qkv_kernel<<<dim3(8, 64), 512, 0, stream>>>(x, WallT, Qp, Kp, Vp);
    attn_kernel<<<512, 512, 0, stream>>>(Qp, Kp, Vp, Pp);
    // out = (P0+P1+P2+P3) @ Wo : fp32 (reduce fused into A-staging)
    gemm_out_kernel<<<dim3(4, 128), 512, 0, stream>>>(Pp, WoT, out);
}